// Round 1
// baseline (779.273 us; speedup 1.0000x reference)
//
#include <hip/hip_runtime.h>
#include <stdint.h>

// ---------------------------------------------------------------------------
// MiniAlignDecoder on MI355X (gfx950)
// B=32, S=1024, D_MODEL=1024, N_LABEL=8192, D_H=64, D_HH=64, N_HEAD=16, N_LAYER=4
//
// Pipeline:
//   1. e (fp32) -> bf16
//   2. w1 -> w1T bf16 (transpose so GEMM reads B^T row-major)
//   3. w2eff = per-64-chunk (w2[:,chunk] @ hyp_w)  -> bf16 [N][K]   (folds hyp linear)
//      beff  = b2_chunk @ hyp_w + hyp_b
//   4. lh = hyperboloid(label), component-major [65][8192] fp32
//   5. GEMM1 (MFMA bf16): X = relu(e@w1+b1), bf16 [32768][2048]
//   6. GEMM2 (MFMA bf16): v = X@w2eff+beff,  bf16 [32768][1024]  (= pre-expmap0 vecs)
//   7. make_kh: per token expmap0 + lift to hyperboloid, kh bf16 [512][65][1024]
//   8. attn: 4 layers distance-softmax + Einstein midpoint (kh0==gamma identity)
//   9. label_mlp: Lorentz distances to 8192 labels + 4-layer MLP + mask
// ---------------------------------------------------------------------------

typedef unsigned short u16;
typedef __attribute__((ext_vector_type(8))) short bh8;
typedef __attribute__((ext_vector_type(4))) float f32x4;

#define DEVI static __device__ __forceinline__

DEVI float bf2f(u16 u) { return __uint_as_float(((unsigned int)u) << 16); }
DEVI u16 f2bfbits(float f) {
  unsigned int x = __float_as_uint(f);
  unsigned int r = x + 0x7fffu + ((x >> 16) & 1u);   // RNE
  return (u16)(r >> 16);
}

typedef __attribute__((address_space(1))) unsigned int gu32;
typedef __attribute__((address_space(3))) unsigned int su32;
DEVI void lds_cp16(const void* g, void* l) {
  __builtin_amdgcn_global_load_lds((gu32*)g, (su32*)l, 16, 0, 0);
}

// ---------------------------------------------------------------------------
// fp32 -> bf16 elementwise (float4 per thread)
__global__ void cvt_bf16x4(const float4* __restrict__ in, ushort4* __restrict__ out, int n4) {
  int i = blockIdx.x * 256 + threadIdx.x;
  if (i >= n4) return;
  float4 f = in[i];
  ushort4 u;
  u.x = f2bfbits(f.x); u.y = f2bfbits(f.y); u.z = f2bfbits(f.z); u.w = f2bfbits(f.w);
  out[i] = u;
}

// ---------------------------------------------------------------------------
// out[C][R] = bf16(in[R][C])  -- LDS-tiled transpose, 64x64 tiles
__global__ __launch_bounds__(256) void transpose_bf16(
    const float* __restrict__ in, u16* __restrict__ out, int R, int C) {
  __shared__ float t[64][65];
  int c0 = blockIdx.x * 64, r0 = blockIdx.y * 64;
  int tx = threadIdx.x & 63, ty = threadIdx.x >> 6;
#pragma unroll
  for (int i = 0; i < 16; i++) {
    int r = i * 4 + ty;
    t[r][tx] = in[(size_t)(r0 + r) * C + c0 + tx];
  }
  __syncthreads();
#pragma unroll
  for (int i = 0; i < 16; i++) {
    int c = i * 4 + ty;
    out[(size_t)(c0 + c) * R + r0 + tx] = f2bfbits(t[tx][c]);
  }
}

// ---------------------------------------------------------------------------
// w2effT[n=ch*64+o][k] = sum_d w2[k][ch*64+d] * hyp_w[d][o]   (bf16, [1024][2048])
__global__ __launch_bounds__(256) void build_w2eff(
    const float* __restrict__ w2, const float* __restrict__ hw, u16* __restrict__ w2effT) {
  __shared__ float W[64 * 64];
  int ch = blockIdx.x >> 3, kb = blockIdx.x & 7;
  for (int i = threadIdx.x; i < 4096; i += 256) W[i] = hw[i];
  __syncthreads();
  int k = kb * 256 + threadIdx.x;
  float row[64];
  const float* rp = w2 + (size_t)k * 1024 + ch * 64;
#pragma unroll
  for (int i = 0; i < 64; i++) row[i] = rp[i];
  for (int o = 0; o < 64; o++) {
    float a = 0.f;
#pragma unroll
    for (int d = 0; d < 64; d++) a += row[d] * W[d * 64 + o];
    w2effT[(size_t)(ch * 64 + o) * 2048 + k] = f2bfbits(a);
  }
}

// beff[n=ch*64+o] = sum_d b2[ch*64+d]*hyp_w[d][o] + hyp_b[o]
__global__ void build_beff(const float* __restrict__ b2, const float* __restrict__ hw,
                           const float* __restrict__ hb, float* __restrict__ beff) {
  int n = blockIdx.x * 256 + threadIdx.x;
  if (n >= 1024) return;
  int ch = n >> 6, o = n & 63;
  float a = hb[o];
#pragma unroll
  for (int d = 0; d < 64; d++) a += b2[ch * 64 + d] * hw[d * 64 + o];
  beff[n] = a;
}

// ---------------------------------------------------------------------------
// lh[65][8192]: hyperboloid lift of label embeddings, component-major
__global__ void make_lh(const float* __restrict__ label, float* __restrict__ lh) {
  int l = blockIdx.x * 256 + threadIdx.x;
  if (l >= 8192) return;
  const float* lp = label + (size_t)l * 64;
  float v[64]; float sq = 0.f;
#pragma unroll
  for (int c = 0; c < 64; c++) { v[c] = lp[c]; sq += v[c] * v[c]; }
  float dd = fmaxf(1.f - sq, 1e-12f);
  lh[l] = (1.f + sq) / dd;
#pragma unroll
  for (int c = 0; c < 64; c++) lh[(size_t)(c + 1) * 8192 + l] = 2.f * v[c] / dd;
}

// ---------------------------------------------------------------------------
// MFMA bf16 GEMM: C[M][N] = op(A[M][K] @ B[K][N] + bias[N]), B given as Bt[N][K].
// 128x128 tile, BK=32, 4 waves (2x2), each wave 4x4 MFMA tiles of 16x16x32.
// m97 structure: global_load_lds width-16 staging, two barriers per K-iter.
template <bool RELU>
__global__ __launch_bounds__(256, 2) void gemm_bf16(
    const u16* __restrict__ A, const u16* __restrict__ Bt,
    const float* __restrict__ bias, u16* __restrict__ C, int N, int K) {
  __shared__ u16 As[128 * 32];
  __shared__ u16 Bs[128 * 32];
  const int tid = threadIdx.x;
  const int wave = tid >> 6, lane = tid & 63;
  const int nblk = N >> 7;
  const int bm = blockIdx.x / nblk, bn = blockIdx.x % nblk;
  const size_t m0 = (size_t)bm * 128;
  const int n0 = bn * 128;
  const int wm = (wave >> 1) << 6, wn = (wave & 1) << 6;
  f32x4 acc[4][4] = {};

  // staging: flat slot j*256+tid -> lds elem *8; row = flat/4, kcol = (flat%4)*8
  const int r0 = tid >> 2, o0 = (tid & 3) << 3;
  const u16* Ap0 = A + (m0 + r0) * K + o0;
  const u16* Ap1 = A + (m0 + 64 + r0) * K + o0;
  const u16* Bp0 = Bt + ((size_t)n0 + r0) * K + o0;
  const u16* Bp1 = Bt + ((size_t)n0 + 64 + r0) * K + o0;
  u16* as0 = As + wave * 512;           // wave-uniform LDS bases (+lane*16B in HW)
  u16* as1 = As + 2048 + wave * 512;
  u16* bs0 = Bs + wave * 512;
  u16* bs1 = Bs + 2048 + wave * 512;

  const int fr = lane & 15, fq = (lane >> 4) << 3;
  for (int kk = 0; kk < K; kk += 32) {
    lds_cp16(Ap0, as0); lds_cp16(Ap1, as1);
    lds_cp16(Bp0, bs0); lds_cp16(Bp1, bs1);
    Ap0 += 32; Ap1 += 32; Bp0 += 32; Bp1 += 32;
    __syncthreads();   // drains vmcnt(0): staged data visible
    bh8 af[4], bfr[4];
#pragma unroll
    for (int t = 0; t < 4; t++) af[t]  = *(const bh8*)(As + (wm + t * 16 + fr) * 32 + fq);
#pragma unroll
    for (int t = 0; t < 4; t++) bfr[t] = *(const bh8*)(Bs + (wn + t * 16 + fr) * 32 + fq);
#pragma unroll
    for (int i = 0; i < 4; i++)
#pragma unroll
      for (int j = 0; j < 4; j++)
        acc[i][j] = __builtin_amdgcn_mfma_f32_16x16x32_bf16(af[i], bfr[j], acc[i][j], 0, 0, 0);
    __syncthreads();   // all waves done reading before next stage overwrites
  }

  // epilogue: C/D layout col=lane&15, row=(lane>>4)*4+reg  [m89-verified]
  const int fq4 = (lane >> 4) << 2;
#pragma unroll
  for (int j = 0; j < 4; j++) {
    int col = n0 + wn + j * 16 + fr;
    float bv = bias[col];
#pragma unroll
    for (int i = 0; i < 4; i++) {
#pragma unroll
      for (int r = 0; r < 4; r++) {
        size_t row = m0 + wm + i * 16 + fq4 + r;
        float v = acc[i][j][r] + bv;
        if (RELU) v = fmaxf(v, 0.f);
        C[row * N + col] = f2bfbits(v);
      }
    }
  }
}

// ---------------------------------------------------------------------------
// make_kh: per token v[64] -> ek = expmap0(v) -> kh = hyperboloid(ek)
// kh layout: [bh=512][c=65][s=1024] bf16 (component-major for coalesced attn reads)
__global__ __launch_bounds__(256) void make_kh(const u16* __restrict__ hv, u16* __restrict__ kh) {
  int bh = blockIdx.x;
  const u16* hb = hv + (size_t)bh * 65536;
  u16* khb = kh + (size_t)bh * 65 * 1024;
  for (int rr = 0; rr < 4; rr++) {
    int s = rr * 256 + threadIdx.x;
    float v[64]; float n2 = 0.f;
    const uint4* rp = (const uint4*)(hb + (size_t)s * 64);
#pragma unroll
    for (int i = 0; i < 8; i++) {
      uint4 d = rp[i];
      unsigned int w[4] = {d.x, d.y, d.z, d.w};
#pragma unroll
      for (int j = 0; j < 4; j++) {
        float a = bf2f((u16)(w[j] & 0xffffu));
        float b = bf2f((u16)(w[j] >> 16));
        v[i * 8 + j * 2]     = a;
        v[i * 8 + j * 2 + 1] = b;
        n2 += a * a + b * b;
      }
    }
    float n = sqrtf(fmaxf(n2, 1e-12f));
    float t = tanhf(n);
    float scale = t / n;          // ek = v*scale, |ek|^2 = t^2
    float sq = t * t;
    float dd = fmaxf(1.f - sq, 1e-12f);
    khb[s] = f2bfbits((1.f + sq) / dd);          // kh0 (== Lorentz gamma)
    float f = 2.f * scale / dd;
#pragma unroll
    for (int c = 0; c < 64; c++) khb[(c + 1) * 1024 + s] = f2bfbits(v[c] * f);
  }
}

// ---------------------------------------------------------------------------
// attention: one block per (b,head). 4 layers of distance-softmax + Einstein midpoint.
// midpoint uses the identity  gamma*vk == kh_spatial, gamma == kh0.
__global__ __launch_bounds__(256) void attn_kernel(
    const u16* __restrict__ kh, const float* __restrict__ label,
    const int* __restrict__ y, const int* __restrict__ mask_text,
    float* __restrict__ qh_out) {
  const int bh = blockIdx.x, b = bh >> 4;
  const int tid = threadIdx.x, lane = tid & 63, wave = tid >> 6;
  __shared__ float q[64], qh[65], sc[1024], w[1024], red[65], rtmp[4];
  __shared__ int msk[1024];
  const u16* khb = kh + (size_t)bh * 65 * 1024;

  for (int i = tid; i < 1024; i += 256) msk[i] = mask_text[b * 1024 + i];
  if (tid < 64) q[tid] = label[(size_t)y[b] * 64 + tid];
  __syncthreads();

  for (int layer = 0; layer < 4; layer++) {
    if (wave == 0) {                          // lift q to hyperboloid
      float qc = q[lane];
      float sq = qc * qc;
      for (int d = 1; d < 64; d <<= 1) sq += __shfl_xor(sq, d);
      float dd = fmaxf(1.f - sq, 1e-12f);
      qh[lane + 1] = 2.f * qc / dd;
      if (lane == 0) qh[0] = (1.f + sq) / dd;
    }
    __syncthreads();
    // scores: inner = sum_spatial qh_c*kh_c - qh0*kh0 ; score = -acosh(max(-inner,1+1e-6))
    float q0 = qh[0];
    float in0, in1, in2, in3;
    {
      float k0 = bf2f(khb[tid]), k1 = bf2f(khb[256 + tid]);
      float k2 = bf2f(khb[512 + tid]), k3 = bf2f(khb[768 + tid]);
      in0 = -q0 * k0; in1 = -q0 * k1; in2 = -q0 * k2; in3 = -q0 * k3;
    }
    for (int c = 1; c < 65; c++) {
      const u16* kc = khb + c * 1024;
      float qc = qh[c];
      in0 += qc * bf2f(kc[tid]);
      in1 += qc * bf2f(kc[256 + tid]);
      in2 += qc * bf2f(kc[512 + tid]);
      in3 += qc * bf2f(kc[768 + tid]);
    }
    float lmax = -3e38f;
    float inn[4] = {in0, in1, in2, in3};
#pragma unroll
    for (int r = 0; r < 4; r++) {
      int s = r * 256 + tid;
      float x = fmaxf(-inn[r], 1.f + 1e-6f);
      float sco = -acoshf(x);
      sco = (msk[s] > 0) ? sco : -1e9f;
      sc[s] = sco;
      lmax = fmaxf(lmax, sco);
    }
    for (int d = 1; d < 64; d <<= 1) lmax = fmaxf(lmax, __shfl_xor(lmax, d));
    if (lane == 0) rtmp[wave] = lmax;
    __syncthreads();
    float m = fmaxf(fmaxf(rtmp[0], rtmp[1]), fmaxf(rtmp[2], rtmp[3]));
#pragma unroll
    for (int r = 0; r < 4; r++) { int s = r * 256 + tid; w[s] = __expf(sc[s] - m); }
    __syncthreads();
    // reduction: red[c] = sum_s w[s]*kh[c][s]; wave handles comps c = wave, wave+4, ...
    for (int c = wave; c < 65; c += 4) {
      const u16* kc = khb + c * 1024;
      float p = 0.f;
#pragma unroll
      for (int k = 0; k < 16; k++) { int s = lane + k * 64; p += w[s] * bf2f(kc[s]); }
      for (int d = 1; d < 64; d <<= 1) p += __shfl_xor(p, d);
      if (lane == 0) red[c] = p;
    }
    __syncthreads();
    if (wave == 0) {                          // Einstein midpoint -> back to Poincare
      float mid = red[lane + 1] / red[0];
      float msq = mid * mid;
      for (int d = 1; d < 64; d <<= 1) msq += __shfl_xor(msq, d);
      q[lane] = mid / (1.f + sqrtf(fmaxf(1.f - msq, 1e-12f)));
    }
    __syncthreads();
  }
  if (wave == 0) {                            // final lift, store qh_out[bh][65]
    float qc = q[lane];
    float sq = qc * qc;
    for (int d = 1; d < 64; d <<= 1) sq += __shfl_xor(sq, d);
    float dd = fmaxf(1.f - sq, 1e-12f);
    qh_out[(size_t)bh * 65 + lane + 1] = 2.f * qc / dd;
    if (lane == 0) qh_out[(size_t)bh * 65] = (1.f + sq) / dd;
  }
}

// ---------------------------------------------------------------------------
// label distances + aggregation MLP. Block: one batch b x 256 labels.
__global__ __launch_bounds__(256) void label_mlp(
    const float* __restrict__ qh, const float* __restrict__ lh,
    const float* __restrict__ w1, const float* __restrict__ b1,
    const float* __restrict__ w2, const float* __restrict__ b2,
    const float* __restrict__ w3, const float* __restrict__ b3,
    const float* __restrict__ w4, const float* __restrict__ b4,
    const int* __restrict__ mask_label, float* __restrict__ out) {
  int blk = blockIdx.x;
  int b = blk >> 5, lb = blk & 31;
  int l = lb * 256 + threadIdx.x;
  __shared__ float qs[16 * 65];
  __shared__ float W1[512], B1[32], W2[1024], B2[32], W3[512], B3[16], W4[16], B4;
  for (int i = threadIdx.x; i < 1040; i += 256) qs[i] = qh[(size_t)b * 1040 + i];
  for (int i = threadIdx.x; i < 512; i += 256)  W1[i] = w1[i];
  for (int i = threadIdx.x; i < 1024; i += 256) W2[i] = w2[i];
  for (int i = threadIdx.x; i < 512; i += 256)  W3[i] = w3[i];
  if (threadIdx.x < 32) { B1[threadIdx.x] = b1[threadIdx.x]; B2[threadIdx.x] = b2[threadIdx.x]; }
  if (threadIdx.x < 16) { B3[threadIdx.x] = b3[threadIdx.x]; W4[threadIdx.x] = w4[threadIdx.x]; }
  if (threadIdx.x == 0) B4 = b4[0];
  __syncthreads();

  float inner[16];
  float l0 = lh[l];
#pragma unroll
  for (int h = 0; h < 16; h++) inner[h] = -qs[h * 65] * l0;
  for (int c = 1; c < 65; c++) {
    float lc = lh[(size_t)c * 8192 + l];
#pragma unroll
    for (int h = 0; h < 16; h++) inner[h] += qs[h * 65 + c] * lc;
  }
  float d[16];
#pragma unroll
  for (int h = 0; h < 16; h++) d[h] = acoshf(fmaxf(-inner[h], 1.f + 1e-6f));

  float x1[32];
#pragma unroll
  for (int o = 0; o < 32; o++) {
    float a = B1[o];
#pragma unroll
    for (int h = 0; h < 16; h++) a += d[h] * W1[h * 32 + o];
    x1[o] = fmaxf(a, 0.f);
  }
  float x2[32];
#pragma unroll
  for (int o = 0; o < 32; o++) {
    float a = B2[o];
#pragma unroll
    for (int i = 0; i < 32; i++) a += x1[i] * W2[i * 32 + o];
    x2[o] = fmaxf(a, 0.f);
  }
  float x3[16];
#pragma unroll
  for (int o = 0; o < 16; o++) {
    float a = B3[o];
#pragma unroll
    for (int i = 0; i < 32; i++) a += x2[i] * W3[i * 16 + o];
    x3[o] = fmaxf(a, 0.f);
  }
  float acc = B4;
#pragma unroll
  for (int h = 0; h < 16; h++) acc += x3[h] * W4[h];
  out[(size_t)b * 8192 + l] = (mask_label[(size_t)b * 8192 + l] > 0) ? acc : -500.0f;
}

// ---------------------------------------------------------------------------
extern "C" void kernel_launch(void* const* d_in, const int* in_sizes, int n_in,
                              void* d_out, int out_size, void* d_ws, size_t ws_size,
                              hipStream_t stream) {
  const float* e     = (const float*)d_in[0];
  const float* label = (const float*)d_in[1];
  const float* tc_w1 = (const float*)d_in[2];
  const float* tc_b1 = (const float*)d_in[3];
  const float* tc_w2 = (const float*)d_in[4];
  const float* tc_b2 = (const float*)d_in[5];
  const float* hyp_w = (const float*)d_in[6];
  const float* hyp_b = (const float*)d_in[7];
  const float* aw1 = (const float*)d_in[8];
  const float* ab1 = (const float*)d_in[9];
  const float* aw2 = (const float*)d_in[10];
  const float* ab2 = (const float*)d_in[11];
  const float* aw3 = (const float*)d_in[12];
  const float* ab3 = (const float*)d_in[13];
  const float* aw4 = (const float*)d_in[14];
  const float* ab4 = (const float*)d_in[15];
  const int* y          = (const int*)d_in[16];
  const int* mask_text  = (const int*)d_in[17];
  const int* mask_label = (const int*)d_in[18];
  float* out = (float*)d_out;

  char* ws = (char*)d_ws;
  // region 0 (134MB): X (bf16 32768x2048), later aliased by kh (65MB)
  // region 1 (64MB):  ebf (bf16 32768x1024), later aliased by hv (bf16 32768x1024)
  u16*   X    = (u16*)(ws + 0);
  u16*   kh   = (u16*)(ws + 0);
  u16*   ebf  = (u16*)(ws + 134217728ull);
  u16*   hv   = (u16*)(ws + 134217728ull);
  u16*   w1T  = (u16*)(ws + 201326592ull);
  u16*   w2eT = (u16*)(ws + 205520896ull);
  float* beff = (float*)(ws + 209715200ull);
  float* lh   = (float*)(ws + 209719296ull);
  float* qh   = (float*)(ws + 211849216ull);

  // 1. conversions / weight prep
  cvt_bf16x4<<<32768, 256, 0, stream>>>((const float4*)e, (ushort4*)ebf, 8388608);
  transpose_bf16<<<dim3(2048 / 64, 1024 / 64), 256, 0, stream>>>(tc_w1, w1T, 1024, 2048);
  build_w2eff<<<128, 256, 0, stream>>>(tc_w2, hyp_w, w2eT);
  build_beff<<<4, 256, 0, stream>>>(tc_b2, hyp_w, hyp_b, beff);
  make_lh<<<32, 256, 0, stream>>>(label, lh);

  // 2. the two big GEMMs
  gemm_bf16<true><<<(32768 / 128) * (2048 / 128), 256, 0, stream>>>(ebf, w1T, tc_b1, X, 2048, 1024);
  gemm_bf16<false><<<(32768 / 128) * (1024 / 128), 256, 0, stream>>>(X, w2eT, beff, hv, 1024, 2048);

  // 3. geometry + attention + head
  make_kh<<<512, 256, 0, stream>>>(hv, kh);
  attn_kernel<<<512, 256, 0, stream>>>(kh, label, y, mask_text, qh);
  label_mlp<<<1024, 256, 0, stream>>>(qh, lh, aw1, ab1, aw2, ab2, aw3, ab3, aw4, ab4,
                                      mask_label, out);
}

// Round 2
// 749.673 us; speedup vs baseline: 1.0395x; 1.0395x over previous
//
#include <hip/hip_runtime.h>
#include <stdint.h>

// ---------------------------------------------------------------------------
// MiniAlignDecoder on MI355X (gfx950)  — Round 2
// R2 changes vs R1:
//  * gemm_bf16: XCD-aware block swizzle (all bn-tiles of a bm-range on one XCD)
//    -> A-strip reuse inside one XCD's L2. FETCH_SIZE 536MB -> ~150MB expected.
//  * attn_kernel: register-resident kh (each thread owns 4 token columns,
//    65 comps packed 2xbf16/uint). kh read ONCE from global instead of 8x.
//    Reductions via 64-lane butterfly + tiny LDS combine. Midpoint+lift fused.
//  * label_mlp: no LDS — all block-uniform operands (qh, W1..W4) read via
//    uniform global indices -> compiler emits s_load (SMEM), kills ~3100
//    broadcast LDS reads per thread.
//  * build_w2eff: same uniform-read trick, float4 row loads.
// ---------------------------------------------------------------------------

typedef unsigned short u16;
typedef __attribute__((ext_vector_type(8))) short bh8;
typedef __attribute__((ext_vector_type(4))) float f32x4;

#define DEVI static __device__ __forceinline__

DEVI float bf2f(u16 u) { return __uint_as_float(((unsigned int)u) << 16); }
DEVI u16 f2bfbits(float f) {
  unsigned int x = __float_as_uint(f);
  unsigned int r = x + 0x7fffu + ((x >> 16) & 1u);   // RNE
  return (u16)(r >> 16);
}

typedef __attribute__((address_space(1))) unsigned int gu32;
typedef __attribute__((address_space(3))) unsigned int su32;
DEVI void lds_cp16(const void* g, void* l) {
  __builtin_amdgcn_global_load_lds((gu32*)g, (su32*)l, 16, 0, 0);
}

// ---------------------------------------------------------------------------
// fp32 -> bf16 elementwise (float4 per thread)
__global__ void cvt_bf16x4(const float4* __restrict__ in, ushort4* __restrict__ out, int n4) {
  int i = blockIdx.x * 256 + threadIdx.x;
  if (i >= n4) return;
  float4 f = in[i];
  ushort4 u;
  u.x = f2bfbits(f.x); u.y = f2bfbits(f.y); u.z = f2bfbits(f.z); u.w = f2bfbits(f.w);
  out[i] = u;
}

// ---------------------------------------------------------------------------
// out[C][R] = bf16(in[R][C])  -- LDS-tiled transpose, 64x64 tiles
__global__ __launch_bounds__(256) void transpose_bf16(
    const float* __restrict__ in, u16* __restrict__ out, int R, int C) {
  __shared__ float t[64][65];
  int c0 = blockIdx.x * 64, r0 = blockIdx.y * 64;
  int tx = threadIdx.x & 63, ty = threadIdx.x >> 6;
#pragma unroll
  for (int i = 0; i < 16; i++) {
    int r = i * 4 + ty;
    t[r][tx] = in[(size_t)(r0 + r) * C + c0 + tx];
  }
  __syncthreads();
#pragma unroll
  for (int i = 0; i < 16; i++) {
    int c = i * 4 + ty;
    out[(size_t)(c0 + c) * R + r0 + tx] = f2bfbits(t[tx][c]);
  }
}

// ---------------------------------------------------------------------------
// w2effT[n=ch*64+o][k] = sum_d w2[k][ch*64+d] * hyp_w[d][o]   (bf16, [1024][2048])
// hyp_w read with uniform indices -> s_load, no LDS.
__global__ __launch_bounds__(256) void build_w2eff(
    const float* __restrict__ w2, const float* __restrict__ hw, u16* __restrict__ w2effT) {
  int ch = blockIdx.x >> 3, kb = blockIdx.x & 7;
  int k = kb * 256 + threadIdx.x;
  float row[64];
  const float4* rp = (const float4*)(w2 + (size_t)k * 1024 + ch * 64);
#pragma unroll
  for (int i = 0; i < 16; i++) {
    float4 f = rp[i];
    row[i * 4] = f.x; row[i * 4 + 1] = f.y; row[i * 4 + 2] = f.z; row[i * 4 + 3] = f.w;
  }
  for (int o = 0; o < 64; o++) {
    float a = 0.f;
#pragma unroll
    for (int d = 0; d < 64; d++) a = fmaf(row[d], hw[d * 64 + o], a);
    w2effT[(size_t)(ch * 64 + o) * 2048 + k] = f2bfbits(a);
  }
}

// beff[n=ch*64+o] = sum_d b2[ch*64+d]*hyp_w[d][o] + hyp_b[o]
__global__ void build_beff(const float* __restrict__ b2, const float* __restrict__ hw,
                           const float* __restrict__ hb, float* __restrict__ beff) {
  int n = blockIdx.x * 256 + threadIdx.x;
  if (n >= 1024) return;
  int ch = n >> 6, o = n & 63;
  float a = hb[o];
#pragma unroll
  for (int d = 0; d < 64; d++) a += b2[ch * 64 + d] * hw[d * 64 + o];
  beff[n] = a;
}

// ---------------------------------------------------------------------------
// lh[65][8192]: hyperboloid lift of label embeddings, component-major
__global__ void make_lh(const float* __restrict__ label, float* __restrict__ lh) {
  int l = blockIdx.x * 256 + threadIdx.x;
  if (l >= 8192) return;
  const float4* lp = (const float4*)(label + (size_t)l * 64);
  float v[64]; float sq = 0.f;
#pragma unroll
  for (int i = 0; i < 16; i++) {
    float4 f = lp[i];
    v[i * 4] = f.x; v[i * 4 + 1] = f.y; v[i * 4 + 2] = f.z; v[i * 4 + 3] = f.w;
    sq += f.x * f.x + f.y * f.y + f.z * f.z + f.w * f.w;
  }
  float dd = fmaxf(1.f - sq, 1e-12f);
  lh[l] = (1.f + sq) / dd;
#pragma unroll
  for (int c = 0; c < 64; c++) lh[(size_t)(c + 1) * 8192 + l] = 2.f * v[c] / dd;
}

// ---------------------------------------------------------------------------
// MFMA bf16 GEMM: C[M][N] = op(A[M][K] @ B[K][N] + bias[N]), B given as Bt[N][K].
// 128x128 tile, BK=32, 4 waves (2x2), 4x4 MFMA 16x16x32 per wave.
// XCD swizzle: blocks g==x (mod 8) land on XCD x; give each XCD a contiguous
// bm-range (all bn) so A-strips + full B stay in that XCD's L2.
template <bool RELU>
__global__ __launch_bounds__(256, 2) void gemm_bf16(
    const u16* __restrict__ A, const u16* __restrict__ Bt,
    const float* __restrict__ bias, u16* __restrict__ C, int N, int K) {
  __shared__ u16 As[128 * 32];
  __shared__ u16 Bs[128 * 32];
  const int tid = threadIdx.x;
  const int wave = tid >> 6, lane = tid & 63;
  const int nblk = N >> 7;
  const int g = blockIdx.x;
  const int xcd = g & 7;
  const int t = g >> 3;
  const int per = (gridDim.x >> 3) / nblk;     // bm rows per XCD
  const int bm = xcd * per + t / nblk;
  const int bn = t % nblk;
  const size_t m0 = (size_t)bm * 128;
  const int n0 = bn * 128;
  const int wm = (wave >> 1) << 6, wn = (wave & 1) << 6;
  f32x4 acc[4][4] = {};

  const int r0 = tid >> 2, o0 = (tid & 3) << 3;
  const u16* Ap0 = A + (m0 + r0) * K + o0;
  const u16* Ap1 = A + (m0 + 64 + r0) * K + o0;
  const u16* Bp0 = Bt + ((size_t)n0 + r0) * K + o0;
  const u16* Bp1 = Bt + ((size_t)n0 + 64 + r0) * K + o0;
  u16* as0 = As + wave * 512;
  u16* as1 = As + 2048 + wave * 512;
  u16* bs0 = Bs + wave * 512;
  u16* bs1 = Bs + 2048 + wave * 512;

  const int fr = lane & 15, fq = (lane >> 4) << 3;
  for (int kk = 0; kk < K; kk += 32) {
    lds_cp16(Ap0, as0); lds_cp16(Ap1, as1);
    lds_cp16(Bp0, bs0); lds_cp16(Bp1, bs1);
    Ap0 += 32; Ap1 += 32; Bp0 += 32; Bp1 += 32;
    __syncthreads();
    bh8 af[4], bfr[4];
#pragma unroll
    for (int t2 = 0; t2 < 4; t2++) af[t2]  = *(const bh8*)(As + (wm + t2 * 16 + fr) * 32 + fq);
#pragma unroll
    for (int t2 = 0; t2 < 4; t2++) bfr[t2] = *(const bh8*)(Bs + (wn + t2 * 16 + fr) * 32 + fq);
#pragma unroll
    for (int i = 0; i < 4; i++)
#pragma unroll
      for (int j = 0; j < 4; j++)
        acc[i][j] = __builtin_amdgcn_mfma_f32_16x16x32_bf16(af[i], bfr[j], acc[i][j], 0, 0, 0);
    __syncthreads();
  }

  const int fq4 = (lane >> 4) << 2;
#pragma unroll
  for (int j = 0; j < 4; j++) {
    int col = n0 + wn + j * 16 + fr;
    float bv = bias[col];
#pragma unroll
    for (int i = 0; i < 4; i++) {
#pragma unroll
      for (int r = 0; r < 4; r++) {
        size_t row = m0 + wm + i * 16 + fq4 + r;
        float v = acc[i][j][r] + bv;
        if (RELU) v = fmaxf(v, 0.f);
        C[row * N + col] = f2bfbits(v);
      }
    }
  }
}

// ---------------------------------------------------------------------------
// make_kh: per token v[64] -> ek = expmap0(v) -> kh = hyperboloid(ek)
// kh layout: [bh=512][c=65][s=1024] bf16
__global__ __launch_bounds__(256) void make_kh(const u16* __restrict__ hv, u16* __restrict__ kh) {
  int bh = blockIdx.x;
  const u16* hb = hv + (size_t)bh * 65536;
  u16* khb = kh + (size_t)bh * 65 * 1024;
  for (int rr = 0; rr < 4; rr++) {
    int s = rr * 256 + threadIdx.x;
    float v[64]; float n2 = 0.f;
    const uint4* rp = (const uint4*)(hb + (size_t)s * 64);
#pragma unroll
    for (int i = 0; i < 8; i++) {
      uint4 d = rp[i];
      unsigned int w[4] = {d.x, d.y, d.z, d.w};
#pragma unroll
      for (int j = 0; j < 4; j++) {
        float a = bf2f((u16)(w[j] & 0xffffu));
        float b = bf2f((u16)(w[j] >> 16));
        v[i * 8 + j * 2]     = a;
        v[i * 8 + j * 2 + 1] = b;
        n2 += a * a + b * b;
      }
    }
    float n = sqrtf(fmaxf(n2, 1e-12f));
    float t = tanhf(n);
    float scale = t / n;
    float sq = t * t;
    float dd = fmaxf(1.f - sq, 1e-12f);
    khb[s] = f2bfbits((1.f + sq) / dd);          // kh0 (== Lorentz gamma)
    float f = 2.f * scale / dd;
#pragma unroll
    for (int c = 0; c < 64; c++) khb[(c + 1) * 1024 + s] = f2bfbits(v[c] * f);
  }
}

// ---------------------------------------------------------------------------
// attention, register-resident kh. One block (256 thr) per (b,head).
// Thread owns s in {tid, 256+tid, 512+tid, 768+tid}: kh0 in fp32,
// spatial comps packed 2xbf16 per uint (32 regs per s).
__global__ __launch_bounds__(256, 2) void attn_kernel(
    const u16* __restrict__ kh, const float* __restrict__ label,
    const int* __restrict__ y, const int* __restrict__ mask_text,
    float* __restrict__ qh_out) {
  const int bh = blockIdx.x, b = bh >> 4;
  const int tid = threadIdx.x, lane = tid & 63, wave = tid >> 6;
  __shared__ float qh[65], rtmp[4], redp[4][65];
  const u16* khb = kh + (size_t)bh * 65 * 1024;

  float kh0[4];
  unsigned int khp[4][32];
  int mt[4];
#pragma unroll
  for (int r = 0; r < 4; r++) {
    int s = r * 256 + tid;
    mt[r] = mask_text[b * 1024 + s];
    kh0[r] = bf2f(khb[s]);
#pragma unroll
    for (int k = 0; k < 32; k++) {
      unsigned int lo = khb[(1 + 2 * k) * 1024 + s];
      unsigned int hi = khb[(2 + 2 * k) * 1024 + s];
      khp[r][k] = lo | (hi << 16);
    }
  }

  // initial lift of q = label[y[b]]
  if (wave == 0) {
    float qv = label[(size_t)y[b] * 64 + lane];
    float sq = qv * qv;
#pragma unroll
    for (int d = 1; d < 64; d <<= 1) sq += __shfl_xor(sq, d);
    float dd = fmaxf(1.f - sq, 1e-12f);
    qh[lane + 1] = 2.f * qv / dd;
    if (lane == 0) qh[0] = (1.f + sq) / dd;
  }
  __syncthreads();

  for (int layer = 0; layer < 4; layer++) {
    // ---- scores from registers
    float q0 = qh[0];
    float inn[4];
#pragma unroll
    for (int r = 0; r < 4; r++) inn[r] = -q0 * kh0[r];
#pragma unroll
    for (int k = 0; k < 32; k++) {
      float qa = qh[1 + 2 * k], qb = qh[2 + 2 * k];
#pragma unroll
      for (int r = 0; r < 4; r++) {
        unsigned int p = khp[r][k];
        inn[r] = fmaf(qa, __uint_as_float(p << 16),
                 fmaf(qb, __uint_as_float(p & 0xffff0000u), inn[r]));
      }
    }
    float w[4]; float lmax = -3e38f;
#pragma unroll
    for (int r = 0; r < 4; r++) {
      float x = fmaxf(-inn[r], 1.f + 1e-6f);
      float sco = -acoshf(x);
      sco = (mt[r] > 0) ? sco : -1e9f;
      w[r] = sco;
      lmax = fmaxf(lmax, sco);
    }
#pragma unroll
    for (int d = 1; d < 64; d <<= 1) lmax = fmaxf(lmax, __shfl_xor(lmax, d));
    if (lane == 0) rtmp[wave] = lmax;
    __syncthreads();
    float m = fmaxf(fmaxf(rtmp[0], rtmp[1]), fmaxf(rtmp[2], rtmp[3]));
#pragma unroll
    for (int r = 0; r < 4; r++) w[r] = __expf(w[r] - m);

    // ---- weighted sums: denom (c=0) + 64 spatial comps, all from registers
    float p0 = w[0] * kh0[0] + w[1] * kh0[1] + w[2] * kh0[2] + w[3] * kh0[3];
#pragma unroll
    for (int d = 1; d < 64; d <<= 1) p0 += __shfl_xor(p0, d);
    if (lane == 0) redp[wave][0] = p0;
#pragma unroll
    for (int k = 0; k < 32; k++) {
      float pa = 0.f, pb = 0.f;
#pragma unroll
      for (int r = 0; r < 4; r++) {
        unsigned int p = khp[r][k];
        pa = fmaf(w[r], __uint_as_float(p << 16), pa);
        pb = fmaf(w[r], __uint_as_float(p & 0xffff0000u), pb);
      }
#pragma unroll
      for (int d = 1; d < 64; d <<= 1) pa += __shfl_xor(pa, d);
#pragma unroll
      for (int d = 1; d < 64; d <<= 1) pb += __shfl_xor(pb, d);
      if (lane == 0) { redp[wave][1 + 2 * k] = pa; redp[wave][2 + 2 * k] = pb; }
    }
    __syncthreads();

    // ---- Einstein midpoint + k2p + hyperboloid lift (fused), wave0 only
    if (wave == 0) {
      float denom = redp[0][0] + redp[1][0] + redp[2][0] + redp[3][0];
      float num = redp[0][lane + 1] + redp[1][lane + 1] + redp[2][lane + 1] + redp[3][lane + 1];
      float mid = num / denom;                 // Klein coords
      float kl = mid * mid;
#pragma unroll
      for (int d = 1; d < 64; d <<= 1) kl += __shfl_xor(kl, d);
      float u = sqrtf(fmaxf(1.f - kl, 1e-12f));
      float pc = mid / (1.f + u);              // Poincare coords
      float sp = kl / ((1.f + u) * (1.f + u)); // |p|^2
      float dd = fmaxf(1.f - sp, 1e-12f);
      qh[lane + 1] = 2.f * pc / dd;
      if (lane == 0) qh[0] = (1.f + sp) / dd;
    }
    __syncthreads();
  }
  if (tid < 65) qh_out[(size_t)bh * 65 + tid] = qh[tid];
}

// ---------------------------------------------------------------------------
// label distances + aggregation MLP. All uniform operands read directly from
// global with wave-uniform indices (compiler -> s_load / scalar cache).
__global__ __launch_bounds__(256) void label_mlp(
    const float* __restrict__ qh, const float* __restrict__ lh,
    const float* __restrict__ w1, const float* __restrict__ b1,
    const float* __restrict__ w2, const float* __restrict__ b2,
    const float* __restrict__ w3, const float* __restrict__ b3,
    const float* __restrict__ w4, const float* __restrict__ b4,
    const int* __restrict__ mask_label, float* __restrict__ out) {
  int blk = blockIdx.x;
  int b = blk >> 5, lb = blk & 31;
  int l = lb * 256 + threadIdx.x;
  const float* qb = qh + (size_t)b * 1040;

  float inner[16];
  float l0 = lh[l];
#pragma unroll
  for (int h = 0; h < 16; h++) inner[h] = -qb[h * 65] * l0;
  for (int c = 1; c < 65; c++) {
    float lc = lh[(size_t)c * 8192 + l];
#pragma unroll
    for (int h = 0; h < 16; h++) inner[h] = fmaf(qb[h * 65 + c], lc, inner[h]);
  }
  float d[16];
#pragma unroll
  for (int h = 0; h < 16; h++) d[h] = acoshf(fmaxf(-inner[h], 1.f + 1e-6f));

  float x1[32];
#pragma unroll
  for (int o = 0; o < 32; o++) {
    float a = b1[o];
#pragma unroll
    for (int h = 0; h < 16; h++) a = fmaf(d[h], w1[h * 32 + o], a);
    x1[o] = fmaxf(a, 0.f);
  }
  float x2[32];
#pragma unroll
  for (int o = 0; o < 32; o++) {
    float a = b2[o];
#pragma unroll
    for (int i = 0; i < 32; i++) a = fmaf(x1[i], w2[i * 32 + o], a);
    x2[o] = fmaxf(a, 0.f);
  }
  float x3[16];
#pragma unroll
  for (int o = 0; o < 16; o++) {
    float a = b3[o];
#pragma unroll
    for (int i = 0; i < 32; i++) a = fmaf(x2[i], w3[i * 16 + o], a);
    x3[o] = fmaxf(a, 0.f);
  }
  float acc = b4[0];
#pragma unroll
  for (int h = 0; h < 16; h++) acc = fmaf(x3[h], w4[h], acc);
  out[(size_t)b * 8192 + l] = (mask_label[(size_t)b * 8192 + l] > 0) ? acc : -500.0f;
}

// ---------------------------------------------------------------------------
extern "C" void kernel_launch(void* const* d_in, const int* in_sizes, int n_in,
                              void* d_out, int out_size, void* d_ws, size_t ws_size,
                              hipStream_t stream) {
  const float* e     = (const float*)d_in[0];
  const float* label = (const float*)d_in[1];
  const float* tc_w1 = (const float*)d_in[2];
  const float* tc_b1 = (const float*)d_in[3];
  const float* tc_w2 = (const float*)d_in[4];
  const float* tc_b2 = (const float*)d_in[5];
  const float* hyp_w = (const float*)d_in[6];
  const float* hyp_b = (const float*)d_in[7];
  const float* aw1 = (const float*)d_in[8];
  const float* ab1 = (const float*)d_in[9];
  const float* aw2 = (const float*)d_in[10];
  const float* ab2 = (const float*)d_in[11];
  const float* aw3 = (const float*)d_in[12];
  const float* ab3 = (const float*)d_in[13];
  const float* aw4 = (const float*)d_in[14];
  const float* ab4 = (const float*)d_in[15];
  const int* y          = (const int*)d_in[16];
  const int* mask_text  = (const int*)d_in[17];
  const int* mask_label = (const int*)d_in[18];
  float* out = (float*)d_out;

  char* ws = (char*)d_ws;
  u16*   X    = (u16*)(ws + 0);                  // 134MB, later aliased by kh (65MB)
  u16*   kh   = (u16*)(ws + 0);
  u16*   ebf  = (u16*)(ws + 134217728ull);       // 64MB, later aliased by hv
  u16*   hv   = (u16*)(ws + 134217728ull);
  u16*   w1T  = (u16*)(ws + 201326592ull);
  u16*   w2eT = (u16*)(ws + 205520896ull);
  float* beff = (float*)(ws + 209715200ull);
  float* lh   = (float*)(ws + 209719296ull);
  float* qh   = (float*)(ws + 211849216ull);

  cvt_bf16x4<<<32768, 256, 0, stream>>>((const float4*)e, (ushort4*)ebf, 8388608);
  transpose_bf16<<<dim3(2048 / 64, 1024 / 64), 256, 0, stream>>>(tc_w1, w1T, 1024, 2048);
  build_w2eff<<<128, 256, 0, stream>>>(tc_w2, hyp_w, w2eT);
  build_beff<<<4, 256, 0, stream>>>(tc_b2, hyp_w, hyp_b, beff);
  make_lh<<<32, 256, 0, stream>>>(label, lh);

  gemm_bf16<true><<<(32768 / 128) * (2048 / 128), 256, 0, stream>>>(ebf, w1T, tc_b1, X, 2048, 1024);
  gemm_bf16<false><<<(32768 / 128) * (1024 / 128), 256, 0, stream>>>(X, w2eT, beff, hv, 1024, 2048);

  make_kh<<<512, 256, 0, stream>>>(hv, kh);
  attn_kernel<<<512, 256, 0, stream>>>(kh, label, y, mask_text, qh);
  label_mlp<<<1024, 256, 0, stream>>>(qh, lh, aw1, ab1, aw2, ab2, aw3, ab3, aw4, ab4,
                                      mask_label, out);
}

// Round 3
// 724.584 us; speedup vs baseline: 1.0755x; 1.0346x over previous
//
#include <hip/hip_runtime.h>
#include <stdint.h>

// ---------------------------------------------------------------------------
// MiniAlignDecoder on MI355X (gfx950)  — Round 3
// R3 changes vs R2:
//  * gemm: BK=64 (2 MFMA k-steps per barrier pair -> half the vmcnt(0) drains),
//    XOR chunk swizzle (o ^ row&7) in staging source + ds_read addrs so the
//    128B-row-stride b128 reads stay conflict-spread. LDS 32 KB/block.
//  * gemm2 epilogue computes expmap0 + hyperboloid lift in-register (16-lane
//    butterfly per 64-dim head row) and writes kh directly — make_kh kernel,
//    hv buffer, and its 128 MB round trip are gone.
//  * prep kernel: transpose(w1) + w2eff + beff + lh + cvt(e->bf16) merged
//    into one launch (roles by blockIdx). 5 kernels total.
//  * lh stored bf16; attn blocks XCD-aligned with gemm2's token->XCD map.
// ---------------------------------------------------------------------------

typedef unsigned short u16;
typedef __attribute__((ext_vector_type(8))) short bh8;
typedef __attribute__((ext_vector_type(4))) float f32x4;

#define DEVI static __device__ __forceinline__

DEVI float bf2f(u16 u) { return __uint_as_float(((unsigned int)u) << 16); }
DEVI u16 f2bfbits(float f) {
  unsigned int x = __float_as_uint(f);
  unsigned int r = x + 0x7fffu + ((x >> 16) & 1u);   // RNE
  return (u16)(r >> 16);
}

typedef __attribute__((address_space(1))) unsigned int gu32;
typedef __attribute__((address_space(3))) unsigned int su32;
DEVI void lds_cp16(const void* g, void* l) {
  __builtin_amdgcn_global_load_lds((gu32*)g, (su32*)l, 16, 0, 0);
}

// ---------------------------------------------------------------------------
// prep: heterogeneous roles by blockIdx.x
//  [0,512)        : w1 [1024][2048] -> w1T bf16 [2048][1024]
//  [512,640)      : w2effT[n][k] = sum_d w2[k][ch*64+d]*hyp_w[d][o], bf16 [1024][2048]
//  640            : beff[n] = b2_chunk @ hyp_w + hyp_b
//  [641,673)      : lh bf16 [65][8192] hyperboloid lift of labels
//  [673,673+8192) : e fp32 -> ebf bf16 (4 float4 per thread)
__global__ __launch_bounds__(256) void prep_kernel(
    const float* __restrict__ e, const float* __restrict__ w1,
    const float* __restrict__ w2, const float* __restrict__ b2,
    const float* __restrict__ hw, const float* __restrict__ hb,
    const float* __restrict__ label,
    u16* __restrict__ ebf, u16* __restrict__ w1T, u16* __restrict__ w2eT,
    float* __restrict__ beff, u16* __restrict__ lh) {
  __shared__ float t[64][65];
  const int blk = blockIdx.x;
  const int tid = threadIdx.x;

  if (blk >= 673) {                       // ---- cvt e -> bf16
    int base = (blk - 673) * 1024 + tid;
    const float4* in = (const float4*)e;
    ushort4* out = (ushort4*)ebf;
#pragma unroll
    for (int j = 0; j < 4; j++) {
      int i = base + j * 256;
      float4 f = in[i];
      ushort4 u;
      u.x = f2bfbits(f.x); u.y = f2bfbits(f.y); u.z = f2bfbits(f.z); u.w = f2bfbits(f.w);
      out[i] = u;
    }
  } else if (blk < 512) {                 // ---- transpose w1 -> w1T
    int c0 = (blk & 31) * 64, r0 = (blk >> 5) * 64;
    int tx = tid & 63, ty = tid >> 6;
#pragma unroll
    for (int i = 0; i < 16; i++) {
      int r = i * 4 + ty;
      t[r][tx] = w1[(size_t)(r0 + r) * 2048 + c0 + tx];
    }
    __syncthreads();
#pragma unroll
    for (int i = 0; i < 16; i++) {
      int c = i * 4 + ty;
      w1T[(size_t)(c0 + c) * 1024 + r0 + tx] = f2bfbits(t[tx][c]);
    }
  } else if (blk < 640) {                 // ---- w2eff
    int bw = blk - 512;
    int ch = bw >> 3, kb = bw & 7;
    int k = kb * 256 + tid;
    float row[64];
    const float4* rp = (const float4*)(w2 + (size_t)k * 1024 + ch * 64);
#pragma unroll
    for (int i = 0; i < 16; i++) {
      float4 f = rp[i];
      row[i * 4] = f.x; row[i * 4 + 1] = f.y; row[i * 4 + 2] = f.z; row[i * 4 + 3] = f.w;
    }
    for (int o = 0; o < 64; o++) {
      float a = 0.f;
#pragma unroll
      for (int d = 0; d < 64; d++) a = fmaf(row[d], hw[d * 64 + o], a);
      w2eT[(size_t)(ch * 64 + o) * 2048 + k] = f2bfbits(a);
    }
  } else if (blk == 640) {                // ---- beff
    for (int n = tid; n < 1024; n += 256) {
      int ch = n >> 6, o = n & 63;
      float a = hb[o];
#pragma unroll
      for (int d = 0; d < 64; d++) a += b2[ch * 64 + d] * hw[d * 64 + o];
      beff[n] = a;
    }
  } else {                                // ---- lh (bf16)
    int l = (blk - 641) * 256 + tid;
    const float4* lp = (const float4*)(label + (size_t)l * 64);
    float v[64]; float sq = 0.f;
#pragma unroll
    for (int i = 0; i < 16; i++) {
      float4 f = lp[i];
      v[i * 4] = f.x; v[i * 4 + 1] = f.y; v[i * 4 + 2] = f.z; v[i * 4 + 3] = f.w;
      sq += f.x * f.x + f.y * f.y + f.z * f.z + f.w * f.w;
    }
    float dd = fmaxf(1.f - sq, 1e-12f);
    lh[l] = f2bfbits((1.f + sq) / dd);
#pragma unroll
    for (int c = 0; c < 64; c++) lh[(size_t)(c + 1) * 8192 + l] = f2bfbits(2.f * v[c] / dd);
  }
}

// ---------------------------------------------------------------------------
// MFMA bf16 GEMM, BK=64, 128x128 tile, 4 waves (2x2), 4x4 MFMA 16x16x32/wave.
// XOR chunk swizzle: LDS pos p of row r holds source chunk p^(r&7); reader of
// chunk o reads pos o^(r&7). Staging stays 128B-coalesced, b128 reads spread
// over all 8 16B bank columns. MODE 0: relu(+bias)->C. MODE 1: fused
// expmap0+hyperboloid epilogue -> kh[bh][65][1024] bf16 (N-tile = 2 heads).
template <int MODE>
__global__ __launch_bounds__(256, 2) void gemm_bk64(
    const u16* __restrict__ A, const u16* __restrict__ Bt,
    const float* __restrict__ bias, u16* __restrict__ C,
    u16* __restrict__ kh, int N, int K) {
  __shared__ u16 As[128 * 64];
  __shared__ u16 Bs[128 * 64];
  const int tid = threadIdx.x;
  const int wave = tid >> 6, lane = tid & 63;
  const int fr = lane & 15, q = lane >> 4;
  const int nblk = N >> 7;
  const int g = blockIdx.x;
  const int xcd = g & 7;
  const int tb = g >> 3;
  const int per = (gridDim.x >> 3) / nblk;     // bm rows per XCD
  const int bm = xcd * per + tb / nblk;
  const int bn = tb % nblk;
  const size_t m0 = (size_t)bm * 128;
  const int n0 = bn * 128;
  const int wm = (wave >> 1) << 6, wn = (wave & 1) << 6;
  f32x4 acc[4][4] = {};

  // staging: call c covers rows [32c,32c+32); lane -> row=tid>>3, chunk slot tid&7,
  // source chunk = slot ^ (row&7).
  const int srow = tid >> 3;
  const int ochunk = (tid & 7) ^ (srow & 7);
  const u16* Ap[4]; const u16* Bp[4];
#pragma unroll
  for (int c = 0; c < 4; c++) {
    Ap[c] = A + (m0 + c * 32 + srow) * (size_t)K + ochunk * 8;
    Bp[c] = Bt + ((size_t)(n0 + c * 32 + srow)) * K + ochunk * 8;
  }

  // fragment ds_read offsets (u16 units), loop-invariant
  int aoff[4][2], boff[4][2];
#pragma unroll
  for (int tt = 0; tt < 4; tt++) {
    int ra = wm + tt * 16 + fr;
    int rb = wn + tt * 16 + fr;
#pragma unroll
    for (int ks = 0; ks < 2; ks++) {
      aoff[tt][ks] = ra * 64 + ((((ks << 2) + q) ^ (ra & 7)) << 3);
      boff[tt][ks] = rb * 64 + ((((ks << 2) + q) ^ (rb & 7)) << 3);
    }
  }

  for (int kk = 0; kk < K; kk += 64) {
#pragma unroll
    for (int c = 0; c < 4; c++) {
      lds_cp16(Ap[c], As + c * 2048 + wave * 512);
      lds_cp16(Bp[c], Bs + c * 2048 + wave * 512);
      Ap[c] += 64; Bp[c] += 64;
    }
    __syncthreads();   // drain: staged data visible
#pragma unroll
    for (int ks = 0; ks < 2; ks++) {
      bh8 af[4], bf[4];
#pragma unroll
      for (int tt = 0; tt < 4; tt++) af[tt] = *(const bh8*)(As + aoff[tt][ks]);
#pragma unroll
      for (int tt = 0; tt < 4; tt++) bf[tt] = *(const bh8*)(Bs + boff[tt][ks]);
#pragma unroll
      for (int i = 0; i < 4; i++)
#pragma unroll
        for (int j = 0; j < 4; j++)
          acc[i][j] = __builtin_amdgcn_mfma_f32_16x16x32_bf16(af[i], bf[j], acc[i][j], 0, 0, 0);
    }
    __syncthreads();   // all waves done reading before next stage overwrites
  }

  // C/D layout: col = n0+wn+j*16+fr, row = m0+wm+i*16+q*4+r  [m89-verified]
  if (MODE == 0) {
#pragma unroll
    for (int j = 0; j < 4; j++) {
      int col = n0 + wn + j * 16 + fr;
      float bv = bias[col];
#pragma unroll
      for (int i = 0; i < 4; i++) {
#pragma unroll
        for (int r = 0; r < 4; r++) {
          size_t row = m0 + wm + i * 16 + q * 4 + r;
          float v = fmaxf(acc[i][j][r] + bv, 0.f);
          C[row * N + col] = f2bfbits(v);
        }
      }
    }
  } else {
    // fused expmap0 + hyperboloid: a wave's 64 cols = one full head.
    const int head = (n0 + wn) >> 6;
    float bv[4];
#pragma unroll
    for (int j = 0; j < 4; j++) bv[j] = bias[n0 + wn + j * 16 + fr];
#pragma unroll
    for (int i = 0; i < 4; i++) {
#pragma unroll
      for (int r = 0; r < 4; r++) {
        int row = (int)m0 + wm + i * 16 + q * 4 + r;
        int b = row >> 10, s = row & 1023;
        float v0 = acc[i][0][r] + bv[0];
        float v1 = acc[i][1][r] + bv[1];
        float v2 = acc[i][2][r] + bv[2];
        float v3 = acc[i][3][r] + bv[3];
        float ss = v0 * v0 + v1 * v1 + v2 * v2 + v3 * v3;
        ss += __shfl_xor(ss, 1); ss += __shfl_xor(ss, 2);
        ss += __shfl_xor(ss, 4); ss += __shfl_xor(ss, 8);   // row norm^2 over 64 dims
        float n = sqrtf(fmaxf(ss, 1e-12f));
        float th = tanhf(n);
        float sq = th * th;
        float dd = fmaxf(1.f - sq, 1e-12f);
        float f = 2.f * (th / n) / dd;
        u16* base = kh + (size_t)(b * 16 + head) * 65 * 1024;
        base[(size_t)(1 + fr) * 1024 + s]  = f2bfbits(v0 * f);
        base[(size_t)(17 + fr) * 1024 + s] = f2bfbits(v1 * f);
        base[(size_t)(33 + fr) * 1024 + s] = f2bfbits(v2 * f);
        base[(size_t)(49 + fr) * 1024 + s] = f2bfbits(v3 * f);
        if (fr == 0) base[s] = f2bfbits((1.f + sq) / dd);   // kh0 (== gamma)
      }
    }
  }
}

// ---------------------------------------------------------------------------
// attention, register-resident kh. One block (256 thr) per (b,head).
// Block->XCD map matches gemm2's token->XCD map (b-quad per XCD) for L2 reuse.
__global__ __launch_bounds__(256, 2) void attn_kernel(
    const u16* __restrict__ kh, const float* __restrict__ label,
    const int* __restrict__ y, const int* __restrict__ mask_text,
    float* __restrict__ qh_out) {
  const int g = blockIdx.x;
  const int b = (g & 7) * 4 + ((g >> 3) & 3);
  const int h = g >> 5;
  const int bh = b * 16 + h;
  const int tid = threadIdx.x, lane = tid & 63, wave = tid >> 6;
  __shared__ float qh[65], rtmp[4], redp[4][65];
  const u16* khb = kh + (size_t)bh * 65 * 1024;

  float kh0[4];
  unsigned int khp[4][32];
  int mt[4];
#pragma unroll
  for (int r = 0; r < 4; r++) {
    int s = r * 256 + tid;
    mt[r] = mask_text[b * 1024 + s];
    kh0[r] = bf2f(khb[s]);
#pragma unroll
    for (int k = 0; k < 32; k++) {
      unsigned int lo = khb[(1 + 2 * k) * 1024 + s];
      unsigned int hi = khb[(2 + 2 * k) * 1024 + s];
      khp[r][k] = lo | (hi << 16);
    }
  }

  if (wave == 0) {                         // initial lift of q = label[y[b]]
    float qv = label[(size_t)y[b] * 64 + lane];
    float sq = qv * qv;
#pragma unroll
    for (int d = 1; d < 64; d <<= 1) sq += __shfl_xor(sq, d);
    float dd = fmaxf(1.f - sq, 1e-12f);
    qh[lane + 1] = 2.f * qv / dd;
    if (lane == 0) qh[0] = (1.f + sq) / dd;
  }
  __syncthreads();

  for (int layer = 0; layer < 4; layer++) {
    float q0 = qh[0];
    float inn[4];
#pragma unroll
    for (int r = 0; r < 4; r++) inn[r] = -q0 * kh0[r];
#pragma unroll
    for (int k = 0; k < 32; k++) {
      float qa = qh[1 + 2 * k], qb = qh[2 + 2 * k];
#pragma unroll
      for (int r = 0; r < 4; r++) {
        unsigned int p = khp[r][k];
        inn[r] = fmaf(qa, __uint_as_float(p << 16),
                 fmaf(qb, __uint_as_float(p & 0xffff0000u), inn[r]));
      }
    }
    float w[4]; float lmax = -3e38f;
#pragma unroll
    for (int r = 0; r < 4; r++) {
      float x = fmaxf(-inn[r], 1.f + 1e-6f);
      float sco = -acoshf(x);
      sco = (mt[r] > 0) ? sco : -1e9f;
      w[r] = sco;
      lmax = fmaxf(lmax, sco);
    }
#pragma unroll
    for (int d = 1; d < 64; d <<= 1) lmax = fmaxf(lmax, __shfl_xor(lmax, d));
    if (lane == 0) rtmp[wave] = lmax;
    __syncthreads();
    float m = fmaxf(fmaxf(rtmp[0], rtmp[1]), fmaxf(rtmp[2], rtmp[3]));
#pragma unroll
    for (int r = 0; r < 4; r++) w[r] = __expf(w[r] - m);

    float p0 = w[0] * kh0[0] + w[1] * kh0[1] + w[2] * kh0[2] + w[3] * kh0[3];
#pragma unroll
    for (int d = 1; d < 64; d <<= 1) p0 += __shfl_xor(p0, d);
    if (lane == 0) redp[wave][0] = p0;
#pragma unroll
    for (int k = 0; k < 32; k++) {
      float pa = 0.f, pb = 0.f;
#pragma unroll
      for (int r = 0; r < 4; r++) {
        unsigned int p = khp[r][k];
        pa = fmaf(w[r], __uint_as_float(p << 16), pa);
        pb = fmaf(w[r], __uint_as_float(p & 0xffff0000u), pb);
      }
#pragma unroll
      for (int d = 1; d < 64; d <<= 1) pa += __shfl_xor(pa, d);
#pragma unroll
      for (int d = 1; d < 64; d <<= 1) pb += __shfl_xor(pb, d);
      if (lane == 0) { redp[wave][1 + 2 * k] = pa; redp[wave][2 + 2 * k] = pb; }
    }
    __syncthreads();

    if (wave == 0) {                       // Einstein midpoint + k2p + lift, fused
      float denom = redp[0][0] + redp[1][0] + redp[2][0] + redp[3][0];
      float num = redp[0][lane + 1] + redp[1][lane + 1] + redp[2][lane + 1] + redp[3][lane + 1];
      float mid = num / denom;             // Klein coords
      float kl = mid * mid;
#pragma unroll
      for (int d = 1; d < 64; d <<= 1) kl += __shfl_xor(kl, d);
      float u = sqrtf(fmaxf(1.f - kl, 1e-12f));
      float pc = mid / (1.f + u);
      float sp = kl / ((1.f + u) * (1.f + u));
      float dd = fmaxf(1.f - sp, 1e-12f);
      qh[lane + 1] = 2.f * pc / dd;
      if (lane == 0) qh[0] = (1.f + sp) / dd;
    }
    __syncthreads();
  }
  if (tid < 65) qh_out[(size_t)bh * 65 + tid] = qh[tid];
}

// ---------------------------------------------------------------------------
// label distances + aggregation MLP. Uniform operands via s_load; lh is bf16.
__global__ __launch_bounds__(256) void label_mlp(
    const float* __restrict__ qh, const u16* __restrict__ lh,
    const float* __restrict__ w1, const float* __restrict__ b1,
    const float* __restrict__ w2, const float* __restrict__ b2,
    const float* __restrict__ w3, const float* __restrict__ b3,
    const float* __restrict__ w4, const float* __restrict__ b4,
    const int* __restrict__ mask_label, float* __restrict__ out) {
  int blk = blockIdx.x;
  int b = blk >> 5, lb = blk & 31;
  int l = lb * 256 + threadIdx.x;
  const float* qb = qh + (size_t)b * 1040;

  float inner[16];
  float l0 = bf2f(lh[l]);
#pragma unroll
  for (int h = 0; h < 16; h++) inner[h] = -qb[h * 65] * l0;
  for (int c = 1; c < 65; c++) {
    float lc = bf2f(lh[(size_t)c * 8192 + l]);
#pragma unroll
    for (int h = 0; h < 16; h++) inner[h] = fmaf(qb[h * 65 + c], lc, inner[h]);
  }
  float d[16];
#pragma unroll
  for (int h = 0; h < 16; h++) d[h] = acoshf(fmaxf(-inner[h], 1.f + 1e-6f));

  float x1[32];
#pragma unroll
  for (int o = 0; o < 32; o++) {
    float a = b1[o];
#pragma unroll
    for (int h = 0; h < 16; h++) a = fmaf(d[h], w1[h * 32 + o], a);
    x1[o] = fmaxf(a, 0.f);
  }
  float x2[32];
#pragma unroll
  for (int o = 0; o < 32; o++) {
    float a = b2[o];
#pragma unroll
    for (int i = 0; i < 32; i++) a = fmaf(x1[i], w2[i * 32 + o], a);
    x2[o] = fmaxf(a, 0.f);
  }
  float x3[16];
#pragma unroll
  for (int o = 0; o < 16; o++) {
    float a = b3[o];
#pragma unroll
    for (int i = 0; i < 32; i++) a = fmaf(x2[i], w3[i * 16 + o], a);
    x3[o] = fmaxf(a, 0.f);
  }
  float acc = b4[0];
#pragma unroll
  for (int h = 0; h < 16; h++) acc = fmaf(x3[h], w4[h], acc);
  out[(size_t)b * 8192 + l] = (mask_label[(size_t)b * 8192 + l] > 0) ? acc : -500.0f;
}

// ---------------------------------------------------------------------------
extern "C" void kernel_launch(void* const* d_in, const int* in_sizes, int n_in,
                              void* d_out, int out_size, void* d_ws, size_t ws_size,
                              hipStream_t stream) {
  const float* e     = (const float*)d_in[0];
  const float* label = (const float*)d_in[1];
  const float* tc_w1 = (const float*)d_in[2];
  const float* tc_b1 = (const float*)d_in[3];
  const float* tc_w2 = (const float*)d_in[4];
  const float* tc_b2 = (const float*)d_in[5];
  const float* hyp_w = (const float*)d_in[6];
  const float* hyp_b = (const float*)d_in[7];
  const float* aw1 = (const float*)d_in[8];
  const float* ab1 = (const float*)d_in[9];
  const float* aw2 = (const float*)d_in[10];
  const float* ab2 = (const float*)d_in[11];
  const float* aw3 = (const float*)d_in[12];
  const float* ab3 = (const float*)d_in[13];
  const float* aw4 = (const float*)d_in[14];
  const float* ab4 = (const float*)d_in[15];
  const int* y          = (const int*)d_in[16];
  const int* mask_text  = (const int*)d_in[17];
  const int* mask_label = (const int*)d_in[18];
  float* out = (float*)d_out;

  char* ws = (char*)d_ws;
  // [0, 134.2MB): X (bf16 32768x2048); qh (133KB) aliases it after gemm2
  // [134.2MB, +68.2MB): ebf (64MB, dead after gemm1) overlapped by kh (68.2MB)
  u16*   X    = (u16*)(ws + 0);
  float* qh   = (float*)(ws + 0);
  u16*   ebf  = (u16*)(ws + 134217728ull);
  u16*   kh   = (u16*)(ws + 134217728ull);
  u16*   w2eT = (u16*)(ws + 202375168ull);
  u16*   w1T  = (u16*)(ws + 206569472ull);
  float* beff = (float*)(ws + 210763776ull);
  u16*   lh   = (u16*)(ws + 210767872ull);   // bf16 [65][8192] = 1.06MB, end ~211.9MB

  prep_kernel<<<673 + 8192, 256, 0, stream>>>(e, tc_w1, tc_w2, tc_b2, hyp_w, hyp_b,
                                              label, ebf, w1T, w2eT, beff, lh);
  gemm_bk64<0><<<4096, 256, 0, stream>>>(ebf, w1T, tc_b1, X, nullptr, 2048, 1024);
  gemm_bk64<1><<<2048, 256, 0, stream>>>(X, w2eT, beff, nullptr, kh, 1024, 2048);
  attn_kernel<<<512, 256, 0, stream>>>(kh, label, y, mask_text, qh);
  label_mlp<<<1024, 256, 0, stream>>>(qh, lh, aw1, ab1, aw2, ab2, aw3, ab3, aw4, ab4,
                                      mask_label, out);
}